// Round 3
// baseline (491.159 us; speedup 1.0000x reference)
//
#include <hip/hip_runtime.h>
#include <hip/hip_bf16.h>
#include <stdint.h>

// ---------------------------------------------------------------------------
// QuantizedLinear: y = x @ (qweight * scale)^T + bias
//   x [8192,4096] f32, qweight [4096,4096] i32 (exact in bf16), out f32.
// bf16 MFMA GEMM, 256x256 tile, BK=64, 8 waves, 4-phase/K-tile schedule,
// m201-depth pipeline: 1 half-tile stage per phase, single vmcnt(6)/K-tile,
// XOR bank swizzle (T2), setprio (T5), XCD-chunked block swizzle (T1).
// ---------------------------------------------------------------------------

#define M_ 8192
#define N_ 4096
#define K_ 4096
#define NT   (K_ / 64)     // 64 K-tiles
#define NTm1 (NT - 1)

typedef __bf16 bf16x8 __attribute__((ext_vector_type(8)));
typedef float  f32x4  __attribute__((ext_vector_type(4)));

typedef __attribute__((address_space(1))) void gvoid_t;
typedef __attribute__((address_space(3))) void lvoid_t;

__device__ __forceinline__ void gload_lds16(const __bf16* g, __bf16* l) {
    __builtin_amdgcn_global_load_lds(
        (gvoid_t*)(uintptr_t)g,
        (lvoid_t*)(uint32_t)(uintptr_t)l, 16, 0, 0);
}

#define BAR()      asm volatile("s_barrier" ::: "memory")
#define VMCNT(n)   asm volatile("s_waitcnt vmcnt(" #n ")" ::: "memory")

// --------------------------- conversion kernels ----------------------------

__global__ __launch_bounds__(256) void k_cvt_x(const float* __restrict__ x,
                                               __bf16* __restrict__ o, int n8) {
    const int stride = gridDim.x * 256;
    for (int i = blockIdx.x * 256 + threadIdx.x; i < n8; i += stride) {
        float4 a = ((const float4*)x)[(size_t)i * 2];
        float4 b = ((const float4*)x)[(size_t)i * 2 + 1];
        bf16x8 r;
        r[0] = (__bf16)a.x; r[1] = (__bf16)a.y; r[2] = (__bf16)a.z; r[3] = (__bf16)a.w;
        r[4] = (__bf16)b.x; r[5] = (__bf16)b.y; r[6] = (__bf16)b.z; r[7] = (__bf16)b.w;
        ((bf16x8*)o)[i] = r;
    }
}

__global__ __launch_bounds__(256) void k_cvt_w(const int* __restrict__ q,
                                               __bf16* __restrict__ o, int n8) {
    const int stride = gridDim.x * 256;
    for (int i = blockIdx.x * 256 + threadIdx.x; i < n8; i += stride) {
        int4 a = ((const int4*)q)[(size_t)i * 2];
        int4 b = ((const int4*)q)[(size_t)i * 2 + 1];
        bf16x8 r;
        r[0] = (__bf16)(float)a.x; r[1] = (__bf16)(float)a.y;
        r[2] = (__bf16)(float)a.z; r[3] = (__bf16)(float)a.w;
        r[4] = (__bf16)(float)b.x; r[5] = (__bf16)(float)b.y;
        r[6] = (__bf16)(float)b.z; r[7] = (__bf16)(float)b.w;
        ((bf16x8*)o)[i] = r;
    }
}

// ------------------------------- GEMM kernel -------------------------------
// LDS (bf16 elems): A slot (d,h) at (d*2+h)*8192; B at 32768 + same.
// Half-tile = 128 rows x 64 k. Swizzle: 16B-slot s stored at s^(row&7).
// Stage ledger (phase -> slot <- K-tile):
//   ph0: A[d^1][1] <- k+1   (slot freed ph3(k-1))
//   ph1: A[d][0]   <- k+2   (freed after ph0(k))
//   ph2: B[d][0]   <- k+2   (freed after ph0(k))
//   ph3: B[d][1]   <- k+2   (freed after ph1(k)); then vmcnt(6) ensures all
//        of K-tile k+1 resident (3 newest half-tile stages may stay in flight).

__global__ __launch_bounds__(512, 2)
void k_gemm(const __bf16* __restrict__ A, const __bf16* __restrict__ B,
            const float* __restrict__ scale, const float* __restrict__ bias,
            float* __restrict__ C) {
    __shared__ __bf16 sm[65536];   // 128 KiB

    const int tid  = threadIdx.x;
    const int lane = tid & 63;
    const int wave = tid >> 6;
    const int wr   = wave >> 2;       // 0..1
    const int wc   = wave & 3;        // 0..3
    const int lr   = lane & 15;
    const int lg   = lane >> 4;       // 0..3

    // T1: XCD-chunked bijective swizzle (512 wgs, 512%8==0 -> simple form)
    const int wg   = blockIdx.x;                  // 0..511
    const int swz  = (wg & 7) * 64 + (wg >> 3);
    const int bx   = swz & 15;                    // N-block 0..15
    const int by   = swz >> 4;                    // M-block 0..31
    const int row0 = by * 256;
    const int col0 = bx * 256;

    __bf16* smA = sm;
    __bf16* smB = sm + 32768;

    f32x4 acc[8][4];
#pragma unroll
    for (int m = 0; m < 8; ++m)
#pragma unroll
        for (int n = 0; n < 4; ++n) acc[m][n] = (f32x4){0.f, 0.f, 0.f, 0.f};

    // staging: chunk q (0..1023) of a half-tile -> LDS elem q*8 (linear dest).
    // logical (row=q>>3, slot=q&7); global 16B block = slot ^ (row&7).
    const int q0 = tid, q1 = tid + 512;
    const int r0 = q0 >> 3, s0 = q0 & 7;
    const int r1 = q1 >> 3, s1 = q1 & 7;
    const int c0 = (s0 ^ (r0 & 7)) * 8;
    const int c1 = (s1 ^ (r1 & 7)) * 8;
    const __bf16* a00 = A + (size_t)(row0 +       r0) * K_ + c0;
    const __bf16* a01 = A + (size_t)(row0 +       r1) * K_ + c1;
    const __bf16* a10 = A + (size_t)(row0 + 128 + r0) * K_ + c0;
    const __bf16* a11 = A + (size_t)(row0 + 128 + r1) * K_ + c1;
    const __bf16* b00 = B + (size_t)(col0 +       r0) * K_ + c0;
    const __bf16* b01 = B + (size_t)(col0 +       r1) * K_ + c1;
    const __bf16* b10 = B + (size_t)(col0 + 128 + r0) * K_ + c0;
    const __bf16* b11 = B + (size_t)(col0 + 128 + r1) * K_ + c1;
    const int la0 = q0 * 8, la1 = q1 * 8;

    auto stageA = [&](int d, int h, int kt) {
        __bf16* dst = smA + (d * 2 + h) * 8192;
        gload_lds16((h ? a10 : a00) + kt * 64, dst + la0);
        gload_lds16((h ? a11 : a01) + kt * 64, dst + la1);
    };
    auto stageB = [&](int d, int h, int kt) {
        __bf16* dst = smB + (d * 2 + h) * 8192;
        gload_lds16((h ? b10 : b00) + kt * 64, dst + la0);
        gload_lds16((h ? b11 : b01) + kt * 64, dst + la1);
    };
    auto rdA = [&](int d, int mh, int m16, int kk) -> bf16x8 {
        const int mrow = wr * 64 + m16 * 16 + lr;
        const int off = (d * 2 + mh) * 8192 + mrow * 64 + (((kk * 4 + lg) ^ (mrow & 7)) * 8);
        return *(const bf16x8*)(smA + off);
    };
    auto rdB = [&](int d, int nh, int n16, int kk) -> bf16x8 {
        const int nrow = wc * 32 + n16 * 16 + lr;
        const int off = (d * 2 + nh) * 8192 + nrow * 64 + (((kk * 4 + lg) ^ (nrow & 7)) * 8);
        return *(const bf16x8*)(smB + off);
    };
    auto MF = [&](bf16x8 a, bf16x8 b, f32x4 c) -> f32x4 {
        return __builtin_amdgcn_mfma_f32_16x16x32_bf16(a, b, c, 0, 0, 0);
    };

    // prologue: K-tile 0 complete (4 half-tiles), then A0,B0,B1 of K-tile 1.
    // vmcnt(6) waits for K-tile 0, leaves the 3 newest stages in flight.
    stageA(0, 0, 0); stageB(0, 0, 0); stageB(0, 1, 0); stageA(0, 1, 0);
    stageA(1, 0, 1); stageB(1, 0, 1); stageB(1, 1, 1);
    VMCNT(6);
    BAR();

    bf16x8 af[4][2];
    bf16x8 bf0[2][2];
    bf16x8 bf1[2][2];

#pragma unroll 2
    for (int k = 0; k < NT; ++k) {
        const int d   = k & 1;
        const int e   = d ^ 1;
        const int kt1 = (k + 1 <= NTm1) ? k + 1 : NTm1;   // clamp -> dead slot
        const int kt2 = (k + 2 <= NTm1) ? k + 2 : NTm1;   // clamp -> dead slot

        // ---- phase 0: quadrant (0,0): reads A[d][0], B[d][0]
#pragma unroll
        for (int m = 0; m < 4; ++m)
#pragma unroll
            for (int kk = 0; kk < 2; ++kk) af[m][kk] = rdA(d, 0, m, kk);
#pragma unroll
        for (int n = 0; n < 2; ++n)
#pragma unroll
            for (int kk = 0; kk < 2; ++kk) bf0[n][kk] = rdB(d, 0, n, kk);
        stageA(e, 1, kt1);
        BAR();
        __builtin_amdgcn_s_setprio(1);
#pragma unroll
        for (int kk = 0; kk < 2; ++kk)
#pragma unroll
            for (int m = 0; m < 4; ++m)
#pragma unroll
                for (int n = 0; n < 2; ++n)
                    acc[m][n] = MF(af[m][kk], bf0[n][kk], acc[m][n]);
        __builtin_amdgcn_s_setprio(0);
        BAR();

        // ---- phase 1: quadrant (0,1): reads B[d][1] (A frags held)
#pragma unroll
        for (int n = 0; n < 2; ++n)
#pragma unroll
            for (int kk = 0; kk < 2; ++kk) bf1[n][kk] = rdB(d, 1, n, kk);
        stageA(d, 0, kt2);
        BAR();
        __builtin_amdgcn_s_setprio(1);
#pragma unroll
        for (int kk = 0; kk < 2; ++kk)
#pragma unroll
            for (int m = 0; m < 4; ++m)
#pragma unroll
                for (int n = 0; n < 2; ++n)
                    acc[m][2 + n] = MF(af[m][kk], bf1[n][kk], acc[m][2 + n]);
        __builtin_amdgcn_s_setprio(0);
        BAR();

        // ---- phase 2: quadrant (1,0): reads A[d][1] (B0 frags held)
#pragma unroll
        for (int m = 0; m < 4; ++m)
#pragma unroll
            for (int kk = 0; kk < 2; ++kk) af[m][kk] = rdA(d, 1, m, kk);
        stageB(d, 0, kt2);
        BAR();
        __builtin_amdgcn_s_setprio(1);
#pragma unroll
        for (int kk = 0; kk < 2; ++kk)
#pragma unroll
            for (int m = 0; m < 4; ++m)
#pragma unroll
                for (int n = 0; n < 2; ++n)
                    acc[4 + m][n] = MF(af[m][kk], bf0[n][kk], acc[4 + m][n]);
        __builtin_amdgcn_s_setprio(0);
        BAR();

        // ---- phase 3: quadrant (1,1): no LDS reads (A1, B1 frags held)
        stageB(d, 1, kt2);
        VMCNT(6);                      // K-tile k+1 fully resident
        BAR();
        __builtin_amdgcn_s_setprio(1);
#pragma unroll
        for (int kk = 0; kk < 2; ++kk)
#pragma unroll
            for (int m = 0; m < 4; ++m)
#pragma unroll
                for (int n = 0; n < 2; ++n)
                    acc[4 + m][2 + n] = MF(af[m][kk], bf1[n][kk], acc[4 + m][2 + n]);
        __builtin_amdgcn_s_setprio(0);
        BAR();
    }

    VMCNT(0);

    // epilogue: frag C/D layout col=lane&15, row=lg*4+j (m89-verified)
    const float s = scale[0];
#pragma unroll
    for (int nh = 0; nh < 2; ++nh)
#pragma unroll
        for (int n16 = 0; n16 < 2; ++n16) {
            const int gc = col0 + nh * 128 + wc * 32 + n16 * 16 + lr;
            const float bv = bias[gc];
#pragma unroll
            for (int mh = 0; mh < 2; ++mh)
#pragma unroll
                for (int m16 = 0; m16 < 4; ++m16) {
                    const int gr = row0 + mh * 128 + wr * 64 + m16 * 16 + lg * 4;
                    const f32x4 v = acc[mh * 4 + m16][nh * 2 + n16];
#pragma unroll
                    for (int j = 0; j < 4; ++j)
                        C[(size_t)(gr + j) * N_ + gc] = v[j] * s + bv;
                }
        }
}

// ------------------------------- launcher ----------------------------------

extern "C" void kernel_launch(void* const* d_in, const int* in_sizes, int n_in,
                              void* d_out, int out_size, void* d_ws, size_t ws_size,
                              hipStream_t stream) {
    const float* x     = (const float*)d_in[0];
    const int*   qw    = (const int*)d_in[1];
    const float* scale = (const float*)d_in[2];
    const float* bias  = (const float*)d_in[3];
    float*       out   = (float*)d_out;

    __bf16* xb = (__bf16*)d_ws;
    __bf16* wb = (__bf16*)((char*)d_ws + (size_t)M_ * K_ * sizeof(__bf16));

    const int n8x = M_ * K_ / 8;
    const int n8w = N_ * K_ / 8;
    k_cvt_x<<<2048, 256, 0, stream>>>(x, xb, n8x);
    k_cvt_w<<<2048, 256, 0, stream>>>(qw, wb, n8w);

    k_gemm<<<512, 512, 0, stream>>>(xb, wb, scale, bias, out);
}